// Round 1
// 177.341 us; speedup vs baseline: 1.0512x; 1.0512x over previous
//
#include <hip/hip_runtime.h>
#include <cmath>

#define TWO_PI_128 0.04908738521234052f  // 2*pi/128

typedef __attribute__((ext_vector_type(8))) short bf16x8;
typedef __attribute__((ext_vector_type(4))) float f32x4;

__device__ inline unsigned short f2bf(float v) {
  unsigned u = __float_as_uint(v);
  unsigned r = (u + 0x7FFFu + ((u >> 16) & 1u)) >> 16;
  return (unsigned short)r;
}

// ---------------------------------------------------------------------------
// Fused front: blocks [0,1024) forward DFT, [1024,3072) weight transpose,
// [3072,3088) temb projection. All three are mutually independent (read only
// kernel inputs), so one launch fills the machine instead of three.
// ---------------------------------------------------------------------------
__global__ __launch_bounds__(256) void front_kernel(
    const float* __restrict__ x, float* __restrict__ xfr_t,
    float* __restrict__ xfi_t, const float* __restrict__ wr,
    const float* __restrict__ wi, float* __restrict__ wt_r,
    float* __restrict__ wt_i, const float* __restrict__ t_emb,
    const float* __restrict__ temb_w, const float* __restrict__ temb_b,
    float* __restrict__ proj) {
  __shared__ union SM {
    struct {
      unsigned short x1[32 * 136];  // [l | 16+l][h], bf16, pad 136
      float red[8 * 256];           // 4 waves x {re,im} partial C
    } f;
    float tile[32][33];
    struct {
      float silu[512];
      float part[64][4];
    } p;
  } sm;

  const int bid = blockIdx.x;
  const int t = threadIdx.x;

  if (bid >= 3072) {
    // ---------------- proj: silu(t_emb) @ temb_w + temb_b ----------------
    const int b = bid - 3072;
    for (int j = t; j < 512; j += 256) {
      float v = t_emb[b * 512 + j];
      sm.p.silu[j] = v / (1.f + __expf(-v));
    }
    __syncthreads();
    const int o = t >> 2, part = t & 3;
    const float* wrow = temb_w + o * 512 + part * 128;
    const float* srow = sm.p.silu + part * 128;
    float acc = 0.f;
#pragma unroll 8
    for (int j = 0; j < 128; ++j) acc = fmaf(srow[j], wrow[j], acc);
    sm.p.part[o][part] = acc;
    __syncthreads();
    if (part == 0) {
      proj[b * 64 + o] = sm.p.part[o][0] + sm.p.part[o][1] + sm.p.part[o][2] +
                         sm.p.part[o][3] + temb_b[o];
    }
    return;
  }

  if (bid >= 1024) {
    // ---------------- weight transpose [io][kl] -> [kl][io] ----------------
    const int flat = bid - 1024;
    const int tensor = flat >> 10;
    const int rem = flat & 1023;
    const int io0 = (rem >> 3) * 32, kl0 = (rem & 7) * 32;
    const float* src = tensor ? wi : wr;
    float* dst = tensor ? wt_i : wt_r;
    const int ty = t >> 3, tx = t & 7;
    float4 v = *(const float4*)(src + (size_t)(io0 + ty) * 256 + kl0 + 4 * tx);
    sm.tile[ty][4 * tx + 0] = v.x;
    sm.tile[ty][4 * tx + 1] = v.y;
    sm.tile[ty][4 * tx + 2] = v.z;
    sm.tile[ty][4 * tx + 3] = v.w;
    __syncthreads();
    float4 o;
    o.x = sm.tile[4 * tx + 0][ty];
    o.y = sm.tile[4 * tx + 1][ty];
    o.z = sm.tile[4 * tx + 2][ty];
    o.w = sm.tile[4 * tx + 3][ty];
    *(float4*)(dst + (size_t)(kl0 + ty) * 4096 + io0 + 4 * tx) = o;
    return;
  }

  // ---------------- forward truncated DFT, one (b,i) plane ----------------
  const int plane = bid;
  const int wv = t >> 6, lane = t & 63, l15 = lane & 15, quad = lane >> 4;

  union U8 {
    bf16x8 v;
    unsigned short u[8];
  };

  float dC, dS;
  sincosf(TWO_PI_128 * (float)l15, &dS, &dC);

  U8 a_re[4], a_im[4];
#pragma unroll
  for (int ks = 0; ks < 4; ++ks) {
    const int w0 = ks * 32 + quad * 8;
    float c, s;
    sincosf(TWO_PI_128 * (float)((l15 * w0) & 127), &s, &c);
#pragma unroll
    for (int j = 0; j < 8; ++j) {
      a_re[ks].u[j] = f2bf(c);
      a_im[ks].u[j] = f2bf(-s);
      float nc = c * dC - s * dS;
      s = s * dC + c * dS;
      c = nc;
    }
  }

  const float* xp = x + (size_t)plane * 16384;
  f32x4 acc[2][2];
#pragma unroll
  for (int mt = 0; mt < 2; ++mt)
#pragma unroll
    for (int nt = 0; nt < 2; ++nt) acc[mt][nt] = (f32x4){0.f, 0.f, 0.f, 0.f};

#pragma unroll
  for (int ks = 0; ks < 4; ++ks) {
#pragma unroll
    for (int nt = 0; nt < 2; ++nt) {
      const float* src =
          xp + (size_t)((wv * 2 + nt) * 16 + l15) * 128 + ks * 32 + quad * 8;
      float4 v0 = *(const float4*)src;
      float4 v1 = *(const float4*)(src + 4);
      U8 bx;
      bx.u[0] = f2bf(v0.x);
      bx.u[1] = f2bf(v0.y);
      bx.u[2] = f2bf(v0.z);
      bx.u[3] = f2bf(v0.w);
      bx.u[4] = f2bf(v1.x);
      bx.u[5] = f2bf(v1.y);
      bx.u[6] = f2bf(v1.z);
      bx.u[7] = f2bf(v1.w);
      acc[0][nt] = __builtin_amdgcn_mfma_f32_16x16x32_bf16(a_re[ks].v, bx.v,
                                                           acc[0][nt], 0, 0, 0);
      acc[1][nt] = __builtin_amdgcn_mfma_f32_16x16x32_bf16(a_im[ks].v, bx.v,
                                                           acc[1][nt], 0, 0, 0);
    }
  }

#pragma unroll
  for (int mt = 0; mt < 2; ++mt)
#pragma unroll
    for (int nt = 0; nt < 2; ++nt)
#pragma unroll
      for (int r = 0; r < 4; ++r)
        sm.f.x1[(mt * 16 + quad * 4 + r) * 136 + (wv * 2 + nt) * 16 + l15] =
            f2bf(acc[mt][nt][r]);
  __syncthreads();

  f32x4 accre = (f32x4){0.f, 0.f, 0.f, 0.f};
  f32x4 accim = (f32x4){0.f, 0.f, 0.f, 0.f};
#pragma unroll
  for (int kl2 = 0; kl2 < 2; ++kl2) {
    const int ks2 = wv * 2 + kl2;
    const int hb = (ks2 & 3) * 32 + quad * 8;
    const int imh = ks2 >> 2;
    float c, s;
    sincosf(TWO_PI_128 * (float)((l15 * hb) & 127), &s, &c);
    U8 ar, ai;
#pragma unroll
    for (int j = 0; j < 8; ++j) {
      if (!imh) {
        ar.u[j] = f2bf(c);
        ai.u[j] = f2bf(-s);
      } else {
        ar.u[j] = f2bf(s);
        ai.u[j] = f2bf(c);
      }
      float nc = c * dC - s * dS;
      s = s * dC + c * dS;
      c = nc;
    }
    bf16x8 bfrag = *(const bf16x8*)(sm.f.x1 + (imh * 16 + l15) * 136 + hb);
    accre =
        __builtin_amdgcn_mfma_f32_16x16x32_bf16(ar.v, bfrag, accre, 0, 0, 0);
    accim =
        __builtin_amdgcn_mfma_f32_16x16x32_bf16(ai.v, bfrag, accim, 0, 0, 0);
  }
  *(f32x4*)(sm.f.red + (wv * 2) * 256 + lane * 4) = accre;
  *(f32x4*)(sm.f.red + (wv * 2 + 1) * 256 + lane * 4) = accim;
  __syncthreads();

  const float re =
      sm.f.red[t] + sm.f.red[512 + t] + sm.f.red[1024 + t] + sm.f.red[1536 + t];
  const float im = sm.f.red[256 + t] + sm.f.red[768 + t] + sm.f.red[1280 + t] +
                   sm.f.red[1792 + t];
  const int k = (t >> 6) * 4 + (t & 3), l = (t >> 2) & 15;
  xfr_t[(size_t)(k * 16 + l) * 1024 + plane] = re * 0.0078125f;
  xfi_t[(size_t)(k * 16 + l) * 1024 + plane] = im * 0.0078125f;
}

// ---------------------------------------------------------------------------
// Mode mix per kl. 1024 threads (16 waves -> 4 waves/SIMD at 1 block/CU);
// each thread computes one (b,o) pair; 4 independent fma chains for ILP.
// ---------------------------------------------------------------------------
__global__ __launch_bounds__(1024) void modemix_kernel(
    const float* __restrict__ xfr_t, const float* __restrict__ xfi_t,
    const float* __restrict__ wt_r, const float* __restrict__ wt_i,
    float* __restrict__ ofr, float* __restrict__ ofi) {
  __shared__ float s_xr[1024], s_xi[1024];  // [b][i]
  __shared__ float s_wr[4096], s_wi[4096];  // [i][o]
  const int kl = blockIdx.x;
  const int t = threadIdx.x;
  if (t < 256)
    ((float4*)s_xr)[t] = ((const float4*)(xfr_t + (size_t)kl * 1024))[t];
  else if (t < 512)
    ((float4*)s_xi)[t - 256] =
        ((const float4*)(xfi_t + (size_t)kl * 1024))[t - 256];
  ((float4*)s_wr)[t] = ((const float4*)(wt_r + (size_t)kl * 4096))[t];
  ((float4*)s_wi)[t] = ((const float4*)(wt_i + (size_t)kl * 4096))[t];
  __syncthreads();
  const int b = t >> 6;
  const int o = t & 63;
  const float* xrp = s_xr + b * 64;
  const float* xip = s_xi + b * 64;
  float ar0 = 0.f, ar1 = 0.f, ai0 = 0.f, ai1 = 0.f;
#pragma unroll 4
  for (int i = 0; i < 64; ++i) {
    float wrv = s_wr[i * 64 + o], wiv = s_wi[i * 64 + o];
    float xr = xrp[i], xi = xip[i];
    ar0 = fmaf(xr, wrv, ar0);
    ar1 = fmaf(xi, wiv, ar1);
    ai0 = fmaf(xr, wiv, ai0);
    ai1 = fmaf(xi, wrv, ai1);
  }
  ofr[(size_t)(b * 64 + o) * 256 + kl] = ar0 - ar1;
  ofi[(size_t)(b * 64 + o) * 256 + kl] = ai0 + ai1;
}

// ---------------------------------------------------------------------------
// Inverse along h. Output: packed bf16 Y[b][h][o][kk], kk=0..15 Yr, 16..31 Yi
// (64 B per (b,h,o) row) — exactly final_kernel's A-fragment staging layout.
// ---------------------------------------------------------------------------
__global__ __launch_bounds__(256) void invh_kernel(
    const float* __restrict__ ofr, const float* __restrict__ ofi,
    uint4* __restrict__ Ybf) {
  __shared__ float s_fr[16 * 260], s_fi[16 * 260];
  __shared__ float2 s_tw[128];
  const int t = threadIdx.x;
  const int bid = blockIdx.x;
  const int b = bid >> 5, og = (bid >> 3) & 3, hg = bid & 7;
  if (t < 128) {
    float sv, cv;
    sincosf(TWO_PI_128 * (float)t, &sv, &cv);
    s_tw[t] = make_float2(cv, sv);
  }
#pragma unroll 4
  for (int pp = 0; pp < 16; ++pp) {
    s_fr[pp * 260 + t] = ofr[(size_t)(b * 64 + og * 16 + pp) * 256 + t];
    s_fi[pp * 260 + t] = ofi[(size_t)(b * 64 + og * 16 + pp) * 256 + t];
  }
  __syncthreads();
  const int ol = t & 15, hl = t >> 4;
  const int h = hg * 16 + hl;
  float yr[16], yi[16];
#pragma unroll
  for (int l = 0; l < 16; ++l) {
    yr[l] = 0.f;
    yi[l] = 0.f;
  }
  const float* FR = s_fr + ol * 260;
  const float* FI = s_fi + ol * 260;
  const float2 tw = s_tw[h];
  float ck = 1.f, sk = 0.f;
#pragma unroll 4
  for (int k = 0; k < 16; ++k) {
#pragma unroll
    for (int q = 0; q < 4; ++q) {
      float4 fr = *(const float4*)(FR + k * 16 + 4 * q);
      float4 fi = *(const float4*)(FI + k * 16 + 4 * q);
      int l = 4 * q;
      yr[l + 0] = fmaf(fr.x, ck, yr[l + 0]);
      yr[l + 0] = fmaf(-fi.x, sk, yr[l + 0]);
      yi[l + 0] = fmaf(fi.x, ck, yi[l + 0]);
      yi[l + 0] = fmaf(fr.x, sk, yi[l + 0]);
      yr[l + 1] = fmaf(fr.y, ck, yr[l + 1]);
      yr[l + 1] = fmaf(-fi.y, sk, yr[l + 1]);
      yi[l + 1] = fmaf(fi.y, ck, yi[l + 1]);
      yi[l + 1] = fmaf(fr.y, sk, yi[l + 1]);
      yr[l + 2] = fmaf(fr.z, ck, yr[l + 2]);
      yr[l + 2] = fmaf(-fi.z, sk, yr[l + 2]);
      yi[l + 2] = fmaf(fi.z, ck, yi[l + 2]);
      yi[l + 2] = fmaf(fr.z, sk, yi[l + 2]);
      yr[l + 3] = fmaf(fr.w, ck, yr[l + 3]);
      yr[l + 3] = fmaf(-fi.w, sk, yr[l + 3]);
      yi[l + 3] = fmaf(fi.w, ck, yi[l + 3]);
      yi[l + 3] = fmaf(fr.w, sk, yi[l + 3]);
    }
    float tt = sk * tw.y, uu = ck * tw.y;
    ck = fmaf(ck, tw.x, -tt);
    sk = fmaf(sk, tw.x, uu);
  }
  unsigned int u[16];
  {
    float sc[16];
    sc[0] = 0.0078125f;
#pragma unroll
    for (int l = 1; l < 16; ++l) sc[l] = 0.015625f;
#pragma unroll
    for (int j = 0; j < 8; ++j) {
      u[j] = (unsigned)f2bf(yr[2 * j] * sc[2 * j]) |
             ((unsigned)f2bf(yr[2 * j + 1] * sc[2 * j + 1]) << 16);
      u[8 + j] = (unsigned)f2bf(yi[2 * j] * sc[2 * j]) |
                 ((unsigned)f2bf(yi[2 * j + 1] * sc[2 * j + 1]) << 16);
    }
  }
  uint4* dst = Ybf + ((size_t)(b * 128 + h) * 64 + og * 16 + ol) * 4;
  dst[0] = make_uint4(u[0], u[1], u[2], u[3]);
  dst[1] = make_uint4(u[4], u[5], u[6], u[7]);
  dst[2] = make_uint4(u[8], u[9], u[10], u[11]);
  dst[3] = make_uint4(u[12], u[13], u[14], u[15]);
}

// ---------------------------------------------------------------------------
// Final fused, MFMA (unchanged).
// ---------------------------------------------------------------------------
__global__ __launch_bounds__(256) void final_kernel(
    const float* __restrict__ x, const float* __restrict__ bw,
    const float* __restrict__ bb, const float* __restrict__ proj,
    const uint4* __restrict__ Ybf, float* __restrict__ out) {
#define AR 104
  __shared__ unsigned short s_A[64 * AR];
  __shared__ float s_bb[64];
  __shared__ float s_pb[64];
  const int h = blockIdx.x, b = blockIdx.y, t = threadIdx.x;

  if (t < 64)
    s_bb[t] = bb[t];
  else if (t < 128)
    s_pb[t - 64] = proj[b * 64 + (t - 64)];

  {
    const int o = t >> 2, q = t & 3;
    const float4* src = (const float4*)(bw + o * 64 + q * 16);
    unsigned int u[8];
#pragma unroll
    for (int m = 0; m < 4; ++m) {
      float4 v = src[m];
      u[2 * m] = (unsigned)f2bf(v.x) | ((unsigned)f2bf(v.y) << 16);
      u[2 * m + 1] = (unsigned)f2bf(v.z) | ((unsigned)f2bf(v.w) << 16);
    }
    uint4* dst = (uint4*)(s_A + o * AR + q * 16);
    dst[0] = make_uint4(u[0], u[1], u[2], u[3]);
    dst[1] = make_uint4(u[4], u[5], u[6], u[7]);
  }
  {
    const int o = t >> 2, q = t & 3;
    uint4 v = Ybf[((size_t)(b * 128 + h) * 64 + o) * 4 + q];
    *(uint4*)(s_A + o * AR + 64 + q * 8) = v;
  }
  __syncthreads();

  const int wv = t >> 6, lane = t & 63;
  const int l15 = lane & 15, quad = lane >> 4;
  const int n0w = wv * 32;

  f32x4 acc[4][2];
#pragma unroll
  for (int mt = 0; mt < 4; ++mt) {
    f32x4 bv = *(const f32x4*)(s_bb + mt * 16 + quad * 4);
    acc[mt][0] = bv;
    acc[mt][1] = bv;
  }

  const float* xrow = x + (size_t)b * 1048576 + (size_t)h * 128 + n0w + l15;
#pragma unroll
  for (int ks = 0; ks < 64; ks += 32) {
    union {
      bf16x8 v;
      unsigned short u[8];
    } bx[2];
#pragma unroll
    for (int nt = 0; nt < 2; ++nt) {
      float xv[8];
#pragma unroll
      for (int j = 0; j < 8; ++j)
        xv[j] = xrow[(size_t)(ks + quad * 8 + j) * 16384 + nt * 16];
#pragma unroll
      for (int j = 0; j < 8; ++j) bx[nt].u[j] = f2bf(xv[j]);
    }
#pragma unroll
    for (int mt = 0; mt < 4; ++mt) {
      bf16x8 a = *(const bf16x8*)(s_A + (mt * 16 + l15) * AR + ks + quad * 8);
      acc[mt][0] = __builtin_amdgcn_mfma_f32_16x16x32_bf16(a, bx[0].v,
                                                           acc[mt][0], 0, 0, 0);
      acc[mt][1] = __builtin_amdgcn_mfma_f32_16x16x32_bf16(a, bx[1].v,
                                                           acc[mt][1], 0, 0, 0);
    }
  }

  {
    const int lbase = (quad & 1) * 8;
    const bool iscos = (quad < 2);
    union {
      bf16x8 v;
      unsigned short u[8];
    } bs[2];
#pragma unroll
    for (int nt = 0; nt < 2; ++nt) {
      const int wn = n0w + nt * 16 + l15;
      float st, ct, ss, cc;
      sincosf(TWO_PI_128 * (float)wn, &st, &ct);
      sincosf(TWO_PI_128 * (float)(wn * lbase), &ss, &cc);
#pragma unroll
      for (int j = 0; j < 8; ++j) {
        bs[nt].u[j] = f2bf(iscos ? cc : -ss);
        float nc = cc * ct - ss * st;
        ss = ss * ct + cc * st;
        cc = nc;
      }
    }
#pragma unroll
    for (int mt = 0; mt < 4; ++mt) {
      bf16x8 a = *(const bf16x8*)(s_A + (mt * 16 + l15) * AR + 64 + quad * 8);
      acc[mt][0] = __builtin_amdgcn_mfma_f32_16x16x32_bf16(a, bs[0].v,
                                                           acc[mt][0], 0, 0, 0);
      acc[mt][1] = __builtin_amdgcn_mfma_f32_16x16x32_bf16(a, bs[1].v,
                                                           acc[mt][1], 0, 0, 0);
    }
  }

#pragma unroll
  for (int mt = 0; mt < 4; ++mt) {
    f32x4 pv = *(const f32x4*)(s_pb + mt * 16 + quad * 4);
#pragma unroll
    for (int nt = 0; nt < 2; ++nt) {
      const int wcol = n0w + nt * 16 + l15;
#pragma unroll
      for (int r = 0; r < 4; ++r) {
        const int o = mt * 16 + quad * 4 + r;
        float v = acc[mt][nt][r];
        float g = fmaf(0.5f * v, 1.f + erff(v * 0.70710678f), pv[r]);
        out[((size_t)(b * 64 + o) * 128 + h) * 128 + wcol] = g;
      }
    }
  }
#undef AR
}

// ---------------------------------------------------------------------------
extern "C" void kernel_launch(void* const* d_in, const int* in_sizes, int n_in,
                              void* d_out, int out_size, void* d_ws,
                              size_t ws_size, hipStream_t stream) {
  (void)in_sizes;
  (void)n_in;
  (void)out_size;
  (void)ws_size;
  const float* x = (const float*)d_in[0];
  const float* t_emb = (const float*)d_in[1];
  const float* wr = (const float*)d_in[2];
  const float* wi = (const float*)d_in[3];
  const float* bw = (const float*)d_in[4];
  const float* bb = (const float*)d_in[5];
  const float* tw = (const float*)d_in[6];
  const float* tb = (const float*)d_in[7];
  float* out = (float*)d_out;

  char* ws = (char*)d_ws;
  float* proj = (float*)(ws);
  float* ofr = (float*)(ws + ((size_t)1 << 20));
  float* ofi = (float*)(ws + ((size_t)2 << 20));
  float* xfr_t = (float*)(ws + ((size_t)3 << 20));
  float* xfi_t = (float*)(ws + ((size_t)4 << 20));
  float* wt_r = (float*)(ws + ((size_t)5 << 20));
  float* wt_i = (float*)(ws + ((size_t)9 << 20));
  uint4* Ybf = (uint4*)(ws + ((size_t)3 << 20));

  front_kernel<<<3088, 256, 0, stream>>>(x, xfr_t, xfi_t, wr, wi, wt_r, wt_i,
                                         t_emb, tw, tb, proj);
  modemix_kernel<<<256, 1024, 0, stream>>>(xfr_t, xfi_t, wt_r, wt_i, ofr, ofi);
  invh_kernel<<<512, 256, 0, stream>>>(ofr, ofi, Ybf);
  final_kernel<<<dim3(128, 16), 256, 0, stream>>>(x, bw, bb, proj, Ybf, out);
}

// Round 2
// 169.890 us; speedup vs baseline: 1.0973x; 1.0439x over previous
//
#include <hip/hip_runtime.h>
#include <cmath>

#define TWO_PI_128 0.04908738521234052f  // 2*pi/128

typedef __attribute__((ext_vector_type(8))) short bf16x8;
typedef __attribute__((ext_vector_type(4))) float f32x4;

__device__ inline unsigned short f2bf(float v) {
  unsigned u = __float_as_uint(v);
  unsigned r = (u + 0x7FFFu + ((u >> 16) & 1u)) >> 16;
  return (unsigned short)r;
}

// ---------------------------------------------------------------------------
// Fused front: blocks [0,1024) forward DFT, [1024,3072) weight transpose,
// [3072,3088) temb projection. All three are mutually independent (read only
// kernel inputs), so one launch fills the machine instead of three.
// ---------------------------------------------------------------------------
__global__ __launch_bounds__(256) void front_kernel(
    const float* __restrict__ x, float* __restrict__ xfr_t,
    float* __restrict__ xfi_t, const float* __restrict__ wr,
    const float* __restrict__ wi, float* __restrict__ wt_r,
    float* __restrict__ wt_i, const float* __restrict__ t_emb,
    const float* __restrict__ temb_w, const float* __restrict__ temb_b,
    float* __restrict__ proj) {
  __shared__ union SM {
    struct {
      unsigned short x1[32 * 136];  // [l | 16+l][h], bf16, pad 136
      float red[8 * 256];           // 4 waves x {re,im} partial C
    } f;
    float tile[32][33];
    struct {
      float silu[512];
      float part[64][4];
    } p;
  } sm;

  const int bid = blockIdx.x;
  const int t = threadIdx.x;

  if (bid >= 3072) {
    // ---------------- proj: silu(t_emb) @ temb_w + temb_b ----------------
    const int b = bid - 3072;
    for (int j = t; j < 512; j += 256) {
      float v = t_emb[b * 512 + j];
      sm.p.silu[j] = v / (1.f + __expf(-v));
    }
    __syncthreads();
    const int o = t >> 2, part = t & 3;
    const float* wrow = temb_w + o * 512 + part * 128;
    const float* srow = sm.p.silu + part * 128;
    float acc = 0.f;
#pragma unroll 8
    for (int j = 0; j < 128; ++j) acc = fmaf(srow[j], wrow[j], acc);
    sm.p.part[o][part] = acc;
    __syncthreads();
    if (part == 0) {
      proj[b * 64 + o] = sm.p.part[o][0] + sm.p.part[o][1] + sm.p.part[o][2] +
                         sm.p.part[o][3] + temb_b[o];
    }
    return;
  }

  if (bid >= 1024) {
    // ---------------- weight transpose [io][kl] -> [kl][io] ----------------
    const int flat = bid - 1024;
    const int tensor = flat >> 10;
    const int rem = flat & 1023;
    const int io0 = (rem >> 3) * 32, kl0 = (rem & 7) * 32;
    const float* src = tensor ? wi : wr;
    float* dst = tensor ? wt_i : wt_r;
    const int ty = t >> 3, tx = t & 7;
    float4 v = *(const float4*)(src + (size_t)(io0 + ty) * 256 + kl0 + 4 * tx);
    sm.tile[ty][4 * tx + 0] = v.x;
    sm.tile[ty][4 * tx + 1] = v.y;
    sm.tile[ty][4 * tx + 2] = v.z;
    sm.tile[ty][4 * tx + 3] = v.w;
    __syncthreads();
    float4 o;
    o.x = sm.tile[4 * tx + 0][ty];
    o.y = sm.tile[4 * tx + 1][ty];
    o.z = sm.tile[4 * tx + 2][ty];
    o.w = sm.tile[4 * tx + 3][ty];
    *(float4*)(dst + (size_t)(kl0 + ty) * 4096 + io0 + 4 * tx) = o;
    return;
  }

  // ---------------- forward truncated DFT, one (b,i) plane ----------------
  const int plane = bid;
  const int wv = t >> 6, lane = t & 63, l15 = lane & 15, quad = lane >> 4;

  union U8 {
    bf16x8 v;
    unsigned short u[8];
  };

  float dC, dS;
  sincosf(TWO_PI_128 * (float)l15, &dS, &dC);

  U8 a_re[4], a_im[4];
#pragma unroll
  for (int ks = 0; ks < 4; ++ks) {
    const int w0 = ks * 32 + quad * 8;
    float c, s;
    sincosf(TWO_PI_128 * (float)((l15 * w0) & 127), &s, &c);
#pragma unroll
    for (int j = 0; j < 8; ++j) {
      a_re[ks].u[j] = f2bf(c);
      a_im[ks].u[j] = f2bf(-s);
      float nc = c * dC - s * dS;
      s = s * dC + c * dS;
      c = nc;
    }
  }

  const float* xp = x + (size_t)plane * 16384;
  f32x4 acc[2][2];
#pragma unroll
  for (int mt = 0; mt < 2; ++mt)
#pragma unroll
    for (int nt = 0; nt < 2; ++nt) acc[mt][nt] = (f32x4){0.f, 0.f, 0.f, 0.f};

#pragma unroll
  for (int ks = 0; ks < 4; ++ks) {
#pragma unroll
    for (int nt = 0; nt < 2; ++nt) {
      const float* src =
          xp + (size_t)((wv * 2 + nt) * 16 + l15) * 128 + ks * 32 + quad * 8;
      float4 v0 = *(const float4*)src;
      float4 v1 = *(const float4*)(src + 4);
      U8 bx;
      bx.u[0] = f2bf(v0.x);
      bx.u[1] = f2bf(v0.y);
      bx.u[2] = f2bf(v0.z);
      bx.u[3] = f2bf(v0.w);
      bx.u[4] = f2bf(v1.x);
      bx.u[5] = f2bf(v1.y);
      bx.u[6] = f2bf(v1.z);
      bx.u[7] = f2bf(v1.w);
      acc[0][nt] = __builtin_amdgcn_mfma_f32_16x16x32_bf16(a_re[ks].v, bx.v,
                                                           acc[0][nt], 0, 0, 0);
      acc[1][nt] = __builtin_amdgcn_mfma_f32_16x16x32_bf16(a_im[ks].v, bx.v,
                                                           acc[1][nt], 0, 0, 0);
    }
  }

#pragma unroll
  for (int mt = 0; mt < 2; ++mt)
#pragma unroll
    for (int nt = 0; nt < 2; ++nt)
#pragma unroll
      for (int r = 0; r < 4; ++r)
        sm.f.x1[(mt * 16 + quad * 4 + r) * 136 + (wv * 2 + nt) * 16 + l15] =
            f2bf(acc[mt][nt][r]);
  __syncthreads();

  f32x4 accre = (f32x4){0.f, 0.f, 0.f, 0.f};
  f32x4 accim = (f32x4){0.f, 0.f, 0.f, 0.f};
#pragma unroll
  for (int kl2 = 0; kl2 < 2; ++kl2) {
    const int ks2 = wv * 2 + kl2;
    const int hb = (ks2 & 3) * 32 + quad * 8;
    const int imh = ks2 >> 2;
    float c, s;
    sincosf(TWO_PI_128 * (float)((l15 * hb) & 127), &s, &c);
    U8 ar, ai;
#pragma unroll
    for (int j = 0; j < 8; ++j) {
      if (!imh) {
        ar.u[j] = f2bf(c);
        ai.u[j] = f2bf(-s);
      } else {
        ar.u[j] = f2bf(s);
        ai.u[j] = f2bf(c);
      }
      float nc = c * dC - s * dS;
      s = s * dC + c * dS;
      c = nc;
    }
    bf16x8 bfrag = *(const bf16x8*)(sm.f.x1 + (imh * 16 + l15) * 136 + hb);
    accre =
        __builtin_amdgcn_mfma_f32_16x16x32_bf16(ar.v, bfrag, accre, 0, 0, 0);
    accim =
        __builtin_amdgcn_mfma_f32_16x16x32_bf16(ai.v, bfrag, accim, 0, 0, 0);
  }
  *(f32x4*)(sm.f.red + (wv * 2) * 256 + lane * 4) = accre;
  *(f32x4*)(sm.f.red + (wv * 2 + 1) * 256 + lane * 4) = accim;
  __syncthreads();

  const float re =
      sm.f.red[t] + sm.f.red[512 + t] + sm.f.red[1024 + t] + sm.f.red[1536 + t];
  const float im = sm.f.red[256 + t] + sm.f.red[768 + t] + sm.f.red[1280 + t] +
                   sm.f.red[1792 + t];
  const int k = (t >> 6) * 4 + (t & 3), l = (t >> 2) & 15;
  xfr_t[(size_t)(k * 16 + l) * 1024 + plane] = re * 0.0078125f;
  xfi_t[(size_t)(k * 16 + l) * 1024 + plane] = im * 0.0078125f;
}

// ---------------------------------------------------------------------------
// Mode mix per kl. 1024 threads (16 waves -> 4 waves/SIMD at 1 block/CU);
// each thread computes one (b,o) pair; 4 independent fma chains for ILP.
// ---------------------------------------------------------------------------
__global__ __launch_bounds__(1024) void modemix_kernel(
    const float* __restrict__ xfr_t, const float* __restrict__ xfi_t,
    const float* __restrict__ wt_r, const float* __restrict__ wt_i,
    float* __restrict__ ofr, float* __restrict__ ofi) {
  __shared__ float s_xr[1024], s_xi[1024];  // [b][i]
  __shared__ float s_wr[4096], s_wi[4096];  // [i][o]
  const int kl = blockIdx.x;
  const int t = threadIdx.x;
  if (t < 256)
    ((float4*)s_xr)[t] = ((const float4*)(xfr_t + (size_t)kl * 1024))[t];
  else if (t < 512)
    ((float4*)s_xi)[t - 256] =
        ((const float4*)(xfi_t + (size_t)kl * 1024))[t - 256];
  ((float4*)s_wr)[t] = ((const float4*)(wt_r + (size_t)kl * 4096))[t];
  ((float4*)s_wi)[t] = ((const float4*)(wt_i + (size_t)kl * 4096))[t];
  __syncthreads();
  const int b = t >> 6;
  const int o = t & 63;
  const float* xrp = s_xr + b * 64;
  const float* xip = s_xi + b * 64;
  float ar0 = 0.f, ar1 = 0.f, ai0 = 0.f, ai1 = 0.f;
#pragma unroll 4
  for (int i = 0; i < 64; ++i) {
    float wrv = s_wr[i * 64 + o], wiv = s_wi[i * 64 + o];
    float xr = xrp[i], xi = xip[i];
    ar0 = fmaf(xr, wrv, ar0);
    ar1 = fmaf(xi, wiv, ar1);
    ai0 = fmaf(xr, wiv, ai0);
    ai1 = fmaf(xi, wrv, ai1);
  }
  ofr[(size_t)(b * 64 + o) * 256 + kl] = ar0 - ar1;
  ofi[(size_t)(b * 64 + o) * 256 + kl] = ai0 + ai1;
}

// ---------------------------------------------------------------------------
// Final fused, MFMA. The k-inverse DFT (formerly invh_kernel) is folded in:
// per block (b,h), Y[o][l] = sum_k of[b,o,k,l] * e^{i 2pi k h/128} is computed
// on the fly (of[b] is 128 KB and L2-resident across the 128 h-blocks of b),
// packed bf16 into the same s_A A-fragment layout as before (bit-identical).
// ---------------------------------------------------------------------------
__global__ __launch_bounds__(256) void final_kernel(
    const float* __restrict__ x, const float* __restrict__ bw,
    const float* __restrict__ bb, const float* __restrict__ proj,
    const float* __restrict__ ofr, const float* __restrict__ ofi,
    float* __restrict__ out) {
#define AR 104
  __shared__ unsigned short s_A[64 * AR];
  __shared__ float s_bb[64];
  __shared__ float s_pb[64];
  const int h = blockIdx.x, b = blockIdx.y, t = threadIdx.x;

  if (t < 64)
    s_bb[t] = bb[t];
  else if (t < 128)
    s_pb[t - 64] = proj[b * 64 + (t - 64)];

  {
    const int o = t >> 2, q = t & 3;
    const float4* src = (const float4*)(bw + o * 64 + q * 16);
    unsigned int u[8];
#pragma unroll
    for (int m = 0; m < 4; ++m) {
      float4 v = src[m];
      u[2 * m] = (unsigned)f2bf(v.x) | ((unsigned)f2bf(v.y) << 16);
      u[2 * m + 1] = (unsigned)f2bf(v.z) | ((unsigned)f2bf(v.w) << 16);
    }
    uint4* dst = (uint4*)(s_A + o * AR + q * 16);
    dst[0] = make_uint4(u[0], u[1], u[2], u[3]);
    dst[1] = make_uint4(u[4], u[5], u[6], u[7]);
  }
  {
    // ---- k-inverse DFT on the fly (replaces invh_kernel) ----
    const int o = t >> 2, lq = t & 3;  // thread covers modes l = lq*4 .. lq*4+3
    const float* FR = ofr + (size_t)(b * 64 + o) * 256 + lq * 4;
    const float* FI = ofi + (size_t)(b * 64 + o) * 256 + lq * 4;
    float dS, dC;
    sincosf(TWO_PI_128 * (float)h, &dS, &dC);
    float ck = 1.f, sk = 0.f;
    float yr[4] = {0.f, 0.f, 0.f, 0.f};
    float yi[4] = {0.f, 0.f, 0.f, 0.f};
#pragma unroll 4
    for (int k = 0; k < 16; ++k) {
      float4 fr = *(const float4*)(FR + k * 16);
      float4 fi = *(const float4*)(FI + k * 16);
      yr[0] = fmaf(fr.x, ck, yr[0]);
      yr[0] = fmaf(-fi.x, sk, yr[0]);
      yi[0] = fmaf(fi.x, ck, yi[0]);
      yi[0] = fmaf(fr.x, sk, yi[0]);
      yr[1] = fmaf(fr.y, ck, yr[1]);
      yr[1] = fmaf(-fi.y, sk, yr[1]);
      yi[1] = fmaf(fi.y, ck, yi[1]);
      yi[1] = fmaf(fr.y, sk, yi[1]);
      yr[2] = fmaf(fr.z, ck, yr[2]);
      yr[2] = fmaf(-fi.z, sk, yr[2]);
      yi[2] = fmaf(fi.z, ck, yi[2]);
      yi[2] = fmaf(fr.z, sk, yi[2]);
      yr[3] = fmaf(fr.w, ck, yr[3]);
      yr[3] = fmaf(-fi.w, sk, yr[3]);
      yi[3] = fmaf(fi.w, ck, yi[3]);
      yi[3] = fmaf(fr.w, sk, yi[3]);
      float tt = sk * dS, uu = ck * dS;
      ck = fmaf(ck, dC, -tt);
      sk = fmaf(sk, dC, uu);
    }
    // scale: mode 0 -> 1/128, modes >0 -> 2/128 (rfft symmetry factor)
    const float scl0 = (lq == 0) ? 0.0078125f : 0.015625f;
    unsigned ur0 = (unsigned)f2bf(yr[0] * scl0) |
                   ((unsigned)f2bf(yr[1] * 0.015625f) << 16);
    unsigned ur1 = (unsigned)f2bf(yr[2] * 0.015625f) |
                   ((unsigned)f2bf(yr[3] * 0.015625f) << 16);
    unsigned ui0 = (unsigned)f2bf(yi[0] * scl0) |
                   ((unsigned)f2bf(yi[1] * 0.015625f) << 16);
    unsigned ui1 = (unsigned)f2bf(yi[2] * 0.015625f) |
                   ((unsigned)f2bf(yi[3] * 0.015625f) << 16);
    *(uint2*)(s_A + o * AR + 64 + lq * 4) = make_uint2(ur0, ur1);
    *(uint2*)(s_A + o * AR + 64 + 16 + lq * 4) = make_uint2(ui0, ui1);
  }
  __syncthreads();

  const int wv = t >> 6, lane = t & 63;
  const int l15 = lane & 15, quad = lane >> 4;
  const int n0w = wv * 32;

  f32x4 acc[4][2];
#pragma unroll
  for (int mt = 0; mt < 4; ++mt) {
    f32x4 bv = *(const f32x4*)(s_bb + mt * 16 + quad * 4);
    acc[mt][0] = bv;
    acc[mt][1] = bv;
  }

  const float* xrow = x + (size_t)b * 1048576 + (size_t)h * 128 + n0w + l15;
#pragma unroll
  for (int ks = 0; ks < 64; ks += 32) {
    union {
      bf16x8 v;
      unsigned short u[8];
    } bx[2];
#pragma unroll
    for (int nt = 0; nt < 2; ++nt) {
      float xv[8];
#pragma unroll
      for (int j = 0; j < 8; ++j)
        xv[j] = xrow[(size_t)(ks + quad * 8 + j) * 16384 + nt * 16];
#pragma unroll
      for (int j = 0; j < 8; ++j) bx[nt].u[j] = f2bf(xv[j]);
    }
#pragma unroll
    for (int mt = 0; mt < 4; ++mt) {
      bf16x8 a = *(const bf16x8*)(s_A + (mt * 16 + l15) * AR + ks + quad * 8);
      acc[mt][0] = __builtin_amdgcn_mfma_f32_16x16x32_bf16(a, bx[0].v,
                                                           acc[mt][0], 0, 0, 0);
      acc[mt][1] = __builtin_amdgcn_mfma_f32_16x16x32_bf16(a, bx[1].v,
                                                           acc[mt][1], 0, 0, 0);
    }
  }

  {
    const int lbase = (quad & 1) * 8;
    const bool iscos = (quad < 2);
    union {
      bf16x8 v;
      unsigned short u[8];
    } bs[2];
#pragma unroll
    for (int nt = 0; nt < 2; ++nt) {
      const int wn = n0w + nt * 16 + l15;
      float st, ct, ss, cc;
      sincosf(TWO_PI_128 * (float)wn, &st, &ct);
      sincosf(TWO_PI_128 * (float)(wn * lbase), &ss, &cc);
#pragma unroll
      for (int j = 0; j < 8; ++j) {
        bs[nt].u[j] = f2bf(iscos ? cc : -ss);
        float nc = cc * ct - ss * st;
        ss = ss * ct + cc * st;
        cc = nc;
      }
    }
#pragma unroll
    for (int mt = 0; mt < 4; ++mt) {
      bf16x8 a = *(const bf16x8*)(s_A + (mt * 16 + l15) * AR + 64 + quad * 8);
      acc[mt][0] = __builtin_amdgcn_mfma_f32_16x16x32_bf16(a, bs[0].v,
                                                           acc[mt][0], 0, 0, 0);
      acc[mt][1] = __builtin_amdgcn_mfma_f32_16x16x32_bf16(a, bs[1].v,
                                                           acc[mt][1], 0, 0, 0);
    }
  }

#pragma unroll
  for (int mt = 0; mt < 4; ++mt) {
    f32x4 pv = *(const f32x4*)(s_pb + mt * 16 + quad * 4);
#pragma unroll
    for (int nt = 0; nt < 2; ++nt) {
      const int wcol = n0w + nt * 16 + l15;
#pragma unroll
      for (int r = 0; r < 4; ++r) {
        const int o = mt * 16 + quad * 4 + r;
        float v = acc[mt][nt][r];
        float g = fmaf(0.5f * v, 1.f + erff(v * 0.70710678f), pv[r]);
        out[((size_t)(b * 64 + o) * 128 + h) * 128 + wcol] = g;
      }
    }
  }
#undef AR
}

// ---------------------------------------------------------------------------
extern "C" void kernel_launch(void* const* d_in, const int* in_sizes, int n_in,
                              void* d_out, int out_size, void* d_ws,
                              size_t ws_size, hipStream_t stream) {
  (void)in_sizes;
  (void)n_in;
  (void)out_size;
  (void)ws_size;
  const float* x = (const float*)d_in[0];
  const float* t_emb = (const float*)d_in[1];
  const float* wr = (const float*)d_in[2];
  const float* wi = (const float*)d_in[3];
  const float* bw = (const float*)d_in[4];
  const float* bb = (const float*)d_in[5];
  const float* tw = (const float*)d_in[6];
  const float* tb = (const float*)d_in[7];
  float* out = (float*)d_out;

  char* ws = (char*)d_ws;
  float* proj = (float*)(ws);
  float* ofr = (float*)(ws + ((size_t)1 << 20));
  float* ofi = (float*)(ws + ((size_t)2 << 20));
  float* xfr_t = (float*)(ws + ((size_t)3 << 20));
  float* xfi_t = (float*)(ws + ((size_t)4 << 20));
  float* wt_r = (float*)(ws + ((size_t)5 << 20));
  float* wt_i = (float*)(ws + ((size_t)9 << 20));

  front_kernel<<<3088, 256, 0, stream>>>(x, xfr_t, xfi_t, wr, wi, wt_r, wt_i,
                                         t_emb, tw, tb, proj);
  modemix_kernel<<<256, 1024, 0, stream>>>(xfr_t, xfi_t, wt_r, wt_i, ofr, ofi);
  final_kernel<<<dim3(128, 16), 256, 0, stream>>>(x, bw, bb, proj, ofr, ofi,
                                                  out);
}

// Round 3
// 168.432 us; speedup vs baseline: 1.1068x; 1.0087x over previous
//
#include <hip/hip_runtime.h>
#include <cmath>

#define TWO_PI_128 0.04908738521234052f  // 2*pi/128

typedef __attribute__((ext_vector_type(8))) short bf16x8;
typedef __attribute__((ext_vector_type(4))) float f32x4;

__device__ inline unsigned short f2bf(float v) {
  unsigned u = __float_as_uint(v);
  unsigned r = (u + 0x7FFFu + ((u >> 16) & 1u)) >> 16;
  return (unsigned short)r;
}

// ---------------------------------------------------------------------------
// Fused front: blocks [0,1024) forward DFT, [1024,3072) weight transpose,
// [3072,3088) temb projection, 3088 twiddle-table builder (Tck, Tspec for
// final_kernel; replicates final's old per-thread recurrences bit-exactly).
// ---------------------------------------------------------------------------
__global__ __launch_bounds__(256) void front_kernel(
    const float* __restrict__ x, float* __restrict__ xfr_t,
    float* __restrict__ xfi_t, const float* __restrict__ wr,
    const float* __restrict__ wi, float* __restrict__ wt_r,
    float* __restrict__ wt_i, const float* __restrict__ t_emb,
    const float* __restrict__ temb_w, const float* __restrict__ temb_b,
    float* __restrict__ proj, float2* __restrict__ Tck,
    unsigned short* __restrict__ Tspec) {
  __shared__ union SM {
    struct {
      unsigned short x1[32 * 136];  // [l | 16+l][h], bf16, pad 136
      float red[8 * 256];           // 4 waves x {re,im} partial C
    } f;
    float tile[32][33];
    struct {
      float silu[512];
      float part[64][4];
    } p;
  } sm;

  const int bid = blockIdx.x;
  const int t = threadIdx.x;

  if (bid >= 3088) {
    // ---------------- twiddle tables for final_kernel ----------------
    if (t < 128) {
      // Tck[h][k]: (ck,sk) sequence, bit-identical to final's old recurrence
      float dS, dC;
      sincosf(TWO_PI_128 * (float)t, &dS, &dC);
      float ck = 1.f, sk = 0.f;
      for (int k = 0; k < 16; ++k) {
        Tck[t * 16 + k] = make_float2(ck, sk);
        float tt = sk * dS, uu = ck * dS;
        ck = fmaf(ck, dC, -tt);
        sk = fmaf(sk, dC, uu);
      }
    } else {
      // Tspec[w][ks]: ks<16 -> cos rows, ks>=16 -> -sin rows (bit-identical
      // to final's old per-thread bs generation).
      const int wn = t - 128;
      float st, ct;
      sincosf(TWO_PI_128 * (float)wn, &st, &ct);
#pragma unroll
      for (int half = 0; half < 2; ++half) {
        float ss, cc;
        sincosf(TWO_PI_128 * (float)(wn * (half * 8)), &ss, &cc);
        for (int j = 0; j < 8; ++j) {
          Tspec[wn * 32 + half * 8 + j] = f2bf(cc);
          Tspec[wn * 32 + 16 + half * 8 + j] = f2bf(-ss);
          float nc = cc * ct - ss * st;
          ss = ss * ct + cc * st;
          cc = nc;
        }
      }
    }
    return;
  }

  if (bid >= 3072) {
    // ---------------- proj: silu(t_emb) @ temb_w + temb_b ----------------
    const int b = bid - 3072;
    for (int j = t; j < 512; j += 256) {
      float v = t_emb[b * 512 + j];
      sm.p.silu[j] = v / (1.f + __expf(-v));
    }
    __syncthreads();
    const int o = t >> 2, part = t & 3;
    const float* wrow = temb_w + o * 512 + part * 128;
    const float* srow = sm.p.silu + part * 128;
    float acc = 0.f;
#pragma unroll 8
    for (int j = 0; j < 128; ++j) acc = fmaf(srow[j], wrow[j], acc);
    sm.p.part[o][part] = acc;
    __syncthreads();
    if (part == 0) {
      proj[b * 64 + o] = sm.p.part[o][0] + sm.p.part[o][1] + sm.p.part[o][2] +
                         sm.p.part[o][3] + temb_b[o];
    }
    return;
  }

  if (bid >= 1024) {
    // ---------------- weight transpose [io][kl] -> [kl][io] ----------------
    const int flat = bid - 1024;
    const int tensor = flat >> 10;
    const int rem = flat & 1023;
    const int io0 = (rem >> 3) * 32, kl0 = (rem & 7) * 32;
    const float* src = tensor ? wi : wr;
    float* dst = tensor ? wt_i : wt_r;
    const int ty = t >> 3, tx = t & 7;
    float4 v = *(const float4*)(src + (size_t)(io0 + ty) * 256 + kl0 + 4 * tx);
    sm.tile[ty][4 * tx + 0] = v.x;
    sm.tile[ty][4 * tx + 1] = v.y;
    sm.tile[ty][4 * tx + 2] = v.z;
    sm.tile[ty][4 * tx + 3] = v.w;
    __syncthreads();
    float4 o;
    o.x = sm.tile[4 * tx + 0][ty];
    o.y = sm.tile[4 * tx + 1][ty];
    o.z = sm.tile[4 * tx + 2][ty];
    o.w = sm.tile[4 * tx + 3][ty];
    *(float4*)(dst + (size_t)(kl0 + ty) * 4096 + io0 + 4 * tx) = o;
    return;
  }

  // ---------------- forward truncated DFT, one (b,i) plane ----------------
  const int plane = bid;
  const int wv = t >> 6, lane = t & 63, l15 = lane & 15, quad = lane >> 4;

  union U8 {
    bf16x8 v;
    unsigned short u[8];
  };

  float dC, dS;
  sincosf(TWO_PI_128 * (float)l15, &dS, &dC);

  U8 a_re[4], a_im[4];
#pragma unroll
  for (int ks = 0; ks < 4; ++ks) {
    const int w0 = ks * 32 + quad * 8;
    float c, s;
    sincosf(TWO_PI_128 * (float)((l15 * w0) & 127), &s, &c);
#pragma unroll
    for (int j = 0; j < 8; ++j) {
      a_re[ks].u[j] = f2bf(c);
      a_im[ks].u[j] = f2bf(-s);
      float nc = c * dC - s * dS;
      s = s * dC + c * dS;
      c = nc;
    }
  }

  const float* xp = x + (size_t)plane * 16384;
  f32x4 acc[2][2];
#pragma unroll
  for (int mt = 0; mt < 2; ++mt)
#pragma unroll
    for (int nt = 0; nt < 2; ++nt) acc[mt][nt] = (f32x4){0.f, 0.f, 0.f, 0.f};

#pragma unroll
  for (int ks = 0; ks < 4; ++ks) {
#pragma unroll
    for (int nt = 0; nt < 2; ++nt) {
      const float* src =
          xp + (size_t)((wv * 2 + nt) * 16 + l15) * 128 + ks * 32 + quad * 8;
      float4 v0 = *(const float4*)src;
      float4 v1 = *(const float4*)(src + 4);
      U8 bx;
      bx.u[0] = f2bf(v0.x);
      bx.u[1] = f2bf(v0.y);
      bx.u[2] = f2bf(v0.z);
      bx.u[3] = f2bf(v0.w);
      bx.u[4] = f2bf(v1.x);
      bx.u[5] = f2bf(v1.y);
      bx.u[6] = f2bf(v1.z);
      bx.u[7] = f2bf(v1.w);
      acc[0][nt] = __builtin_amdgcn_mfma_f32_16x16x32_bf16(a_re[ks].v, bx.v,
                                                           acc[0][nt], 0, 0, 0);
      acc[1][nt] = __builtin_amdgcn_mfma_f32_16x16x32_bf16(a_im[ks].v, bx.v,
                                                           acc[1][nt], 0, 0, 0);
    }
  }

#pragma unroll
  for (int mt = 0; mt < 2; ++mt)
#pragma unroll
    for (int nt = 0; nt < 2; ++nt)
#pragma unroll
      for (int r = 0; r < 4; ++r)
        sm.f.x1[(mt * 16 + quad * 4 + r) * 136 + (wv * 2 + nt) * 16 + l15] =
            f2bf(acc[mt][nt][r]);
  __syncthreads();

  f32x4 accre = (f32x4){0.f, 0.f, 0.f, 0.f};
  f32x4 accim = (f32x4){0.f, 0.f, 0.f, 0.f};
#pragma unroll
  for (int kl2 = 0; kl2 < 2; ++kl2) {
    const int ks2 = wv * 2 + kl2;
    const int hb = (ks2 & 3) * 32 + quad * 8;
    const int imh = ks2 >> 2;
    float c, s;
    sincosf(TWO_PI_128 * (float)((l15 * hb) & 127), &s, &c);
    U8 ar, ai;
#pragma unroll
    for (int j = 0; j < 8; ++j) {
      if (!imh) {
        ar.u[j] = f2bf(c);
        ai.u[j] = f2bf(-s);
      } else {
        ar.u[j] = f2bf(s);
        ai.u[j] = f2bf(c);
      }
      float nc = c * dC - s * dS;
      s = s * dC + c * dS;
      c = nc;
    }
    bf16x8 bfrag = *(const bf16x8*)(sm.f.x1 + (imh * 16 + l15) * 136 + hb);
    accre =
        __builtin_amdgcn_mfma_f32_16x16x32_bf16(ar.v, bfrag, accre, 0, 0, 0);
    accim =
        __builtin_amdgcn_mfma_f32_16x16x32_bf16(ai.v, bfrag, accim, 0, 0, 0);
  }
  *(f32x4*)(sm.f.red + (wv * 2) * 256 + lane * 4) = accre;
  *(f32x4*)(sm.f.red + (wv * 2 + 1) * 256 + lane * 4) = accim;
  __syncthreads();

  const float re =
      sm.f.red[t] + sm.f.red[512 + t] + sm.f.red[1024 + t] + sm.f.red[1536 + t];
  const float im = sm.f.red[256 + t] + sm.f.red[768 + t] + sm.f.red[1280 + t] +
                   sm.f.red[1792 + t];
  const int k = (t >> 6) * 4 + (t & 3), l = (t >> 2) & 15;
  xfr_t[(size_t)(k * 16 + l) * 1024 + plane] = re * 0.0078125f;
  xfi_t[(size_t)(k * 16 + l) * 1024 + plane] = im * 0.0078125f;
}

// ---------------------------------------------------------------------------
// Mode mix per kl (unchanged).
// ---------------------------------------------------------------------------
__global__ __launch_bounds__(1024) void modemix_kernel(
    const float* __restrict__ xfr_t, const float* __restrict__ xfi_t,
    const float* __restrict__ wt_r, const float* __restrict__ wt_i,
    float* __restrict__ ofr, float* __restrict__ ofi) {
  __shared__ float s_xr[1024], s_xi[1024];  // [b][i]
  __shared__ float s_wr[4096], s_wi[4096];  // [i][o]
  const int kl = blockIdx.x;
  const int t = threadIdx.x;
  if (t < 256)
    ((float4*)s_xr)[t] = ((const float4*)(xfr_t + (size_t)kl * 1024))[t];
  else if (t < 512)
    ((float4*)s_xi)[t - 256] =
        ((const float4*)(xfi_t + (size_t)kl * 1024))[t - 256];
  ((float4*)s_wr)[t] = ((const float4*)(wt_r + (size_t)kl * 4096))[t];
  ((float4*)s_wi)[t] = ((const float4*)(wt_i + (size_t)kl * 4096))[t];
  __syncthreads();
  const int b = t >> 6;
  const int o = t & 63;
  const float* xrp = s_xr + b * 64;
  const float* xip = s_xi + b * 64;
  float ar0 = 0.f, ar1 = 0.f, ai0 = 0.f, ai1 = 0.f;
#pragma unroll 4
  for (int i = 0; i < 64; ++i) {
    float wrv = s_wr[i * 64 + o], wiv = s_wi[i * 64 + o];
    float xr = xrp[i], xi = xip[i];
    ar0 = fmaf(xr, wrv, ar0);
    ar1 = fmaf(xi, wiv, ar1);
    ai0 = fmaf(xr, wiv, ai0);
    ai1 = fmaf(xi, wrv, ai1);
  }
  ofr[(size_t)(b * 64 + o) * 256 + kl] = ar0 - ar1;
  ofi[(size_t)(b * 64 + o) * 256 + kl] = ai0 + ai1;
}

// ---------------------------------------------------------------------------
// Final fused, MFMA. Changes vs R2:
//  - 32 x-loads hoisted to registers at kernel top (HBM latency hidden under
//    the of-DFT staging phase; consumed after the sync).
//  - spectral B-fragments loaded from the precomputed Tspec table (global,
//    L2-resident 8 KB) instead of 2 sincosf + 16-step recurrence per thread.
//  - of-DFT twiddles (ck,sk) read from Tck table (bit-identical values),
//    removing the serial 16-step recurrence from the staging loop.
// ---------------------------------------------------------------------------
__global__ __launch_bounds__(256, 4) void final_kernel(
    const float* __restrict__ x, const float* __restrict__ bw,
    const float* __restrict__ bb, const float* __restrict__ proj,
    const float* __restrict__ ofr, const float* __restrict__ ofi,
    const float2* __restrict__ Tck, const unsigned short* __restrict__ Tspec,
    float* __restrict__ out) {
#define AR 104
  __shared__ unsigned short s_A[64 * AR];
  __shared__ float s_bb[64];
  __shared__ float s_pb[64];
  const int h = blockIdx.x, b = blockIdx.y, t = threadIdx.x;
  const int wv = t >> 6, lane = t & 63;
  const int l15 = lane & 15, quad = lane >> 4;
  const int n0w = wv * 32;

  // ---- hoisted x loads: issued first, consumed after the sync ----
  float xv[32];
  {
    const float* xbase = x + (size_t)b * 1048576 + (size_t)h * 128;
#pragma unroll
    for (int ks2 = 0; ks2 < 2; ++ks2)
#pragma unroll
      for (int nt = 0; nt < 2; ++nt)
#pragma unroll
        for (int j = 0; j < 8; ++j)
          xv[(ks2 * 2 + nt) * 8 + j] =
              xbase[(size_t)(ks2 * 32 + quad * 8 + j) * 16384 + n0w + nt * 16 +
                    l15];
  }

  // ---- spectral B-fragments from table (2 x 16B per thread) ----
  bf16x8 tsf[2];
#pragma unroll
  for (int nt = 0; nt < 2; ++nt)
    tsf[nt] = *(const bf16x8*)(Tspec + (n0w + nt * 16 + l15) * 32 + quad * 8);

  if (t < 64)
    s_bb[t] = bb[t];
  else if (t < 128)
    s_pb[t - 64] = proj[b * 64 + (t - 64)];

  {
    const int o = t >> 2, q = t & 3;
    const float4* src = (const float4*)(bw + o * 64 + q * 16);
    unsigned int u[8];
#pragma unroll
    for (int m = 0; m < 4; ++m) {
      float4 v = src[m];
      u[2 * m] = (unsigned)f2bf(v.x) | ((unsigned)f2bf(v.y) << 16);
      u[2 * m + 1] = (unsigned)f2bf(v.z) | ((unsigned)f2bf(v.w) << 16);
    }
    uint4* dst = (uint4*)(s_A + o * AR + q * 16);
    dst[0] = make_uint4(u[0], u[1], u[2], u[3]);
    dst[1] = make_uint4(u[4], u[5], u[6], u[7]);
  }
  {
    // ---- k-inverse DFT staging with table twiddles ----
    const int o = t >> 2, lq = t & 3;  // thread covers modes l = lq*4..lq*4+3
    const float* FR = ofr + (size_t)(b * 64 + o) * 256 + lq * 4;
    const float* FI = ofi + (size_t)(b * 64 + o) * 256 + lq * 4;
    const float2* tckrow = Tck + h * 16;
    float yr[4] = {0.f, 0.f, 0.f, 0.f};
    float yi[4] = {0.f, 0.f, 0.f, 0.f};
#pragma unroll 4
    for (int k = 0; k < 16; ++k) {
      float4 fr = *(const float4*)(FR + k * 16);
      float4 fi = *(const float4*)(FI + k * 16);
      const float2 cs = tckrow[k];
      const float ck = cs.x, sk = cs.y;
      yr[0] = fmaf(fr.x, ck, yr[0]);
      yr[0] = fmaf(-fi.x, sk, yr[0]);
      yi[0] = fmaf(fi.x, ck, yi[0]);
      yi[0] = fmaf(fr.x, sk, yi[0]);
      yr[1] = fmaf(fr.y, ck, yr[1]);
      yr[1] = fmaf(-fi.y, sk, yr[1]);
      yi[1] = fmaf(fi.y, ck, yi[1]);
      yi[1] = fmaf(fr.y, sk, yi[1]);
      yr[2] = fmaf(fr.z, ck, yr[2]);
      yr[2] = fmaf(-fi.z, sk, yr[2]);
      yi[2] = fmaf(fi.z, ck, yi[2]);
      yi[2] = fmaf(fr.z, sk, yi[2]);
      yr[3] = fmaf(fr.w, ck, yr[3]);
      yr[3] = fmaf(-fi.w, sk, yr[3]);
      yi[3] = fmaf(fi.w, ck, yi[3]);
      yi[3] = fmaf(fr.w, sk, yi[3]);
    }
    // scale: mode 0 -> 1/128, modes >0 -> 2/128 (rfft symmetry factor)
    const float scl0 = (lq == 0) ? 0.0078125f : 0.015625f;
    unsigned ur0 = (unsigned)f2bf(yr[0] * scl0) |
                   ((unsigned)f2bf(yr[1] * 0.015625f) << 16);
    unsigned ur1 = (unsigned)f2bf(yr[2] * 0.015625f) |
                   ((unsigned)f2bf(yr[3] * 0.015625f) << 16);
    unsigned ui0 = (unsigned)f2bf(yi[0] * scl0) |
                   ((unsigned)f2bf(yi[1] * 0.015625f) << 16);
    unsigned ui1 = (unsigned)f2bf(yi[2] * 0.015625f) |
                   ((unsigned)f2bf(yi[3] * 0.015625f) << 16);
    *(uint2*)(s_A + o * AR + 64 + lq * 4) = make_uint2(ur0, ur1);
    *(uint2*)(s_A + o * AR + 64 + 16 + lq * 4) = make_uint2(ui0, ui1);
  }
  __syncthreads();

  f32x4 acc[4][2];
#pragma unroll
  for (int mt = 0; mt < 4; ++mt) {
    f32x4 bv = *(const f32x4*)(s_bb + mt * 16 + quad * 4);
    acc[mt][0] = bv;
    acc[mt][1] = bv;
  }

  // ---- bypass MFMA: B-operand from hoisted registers ----
#pragma unroll
  for (int ks2 = 0; ks2 < 2; ++ks2) {
    union {
      bf16x8 v;
      unsigned short u[8];
    } bx[2];
#pragma unroll
    for (int nt = 0; nt < 2; ++nt)
#pragma unroll
      for (int j = 0; j < 8; ++j)
        bx[nt].u[j] = f2bf(xv[(ks2 * 2 + nt) * 8 + j]);
#pragma unroll
    for (int mt = 0; mt < 4; ++mt) {
      bf16x8 a =
          *(const bf16x8*)(s_A + (mt * 16 + l15) * AR + ks2 * 32 + quad * 8);
      acc[mt][0] = __builtin_amdgcn_mfma_f32_16x16x32_bf16(a, bx[0].v,
                                                           acc[mt][0], 0, 0, 0);
      acc[mt][1] = __builtin_amdgcn_mfma_f32_16x16x32_bf16(a, bx[1].v,
                                                           acc[mt][1], 0, 0, 0);
    }
  }

  // ---- spectral MFMA: B-operand from Tspec table ----
#pragma unroll
  for (int mt = 0; mt < 4; ++mt) {
    bf16x8 a = *(const bf16x8*)(s_A + (mt * 16 + l15) * AR + 64 + quad * 8);
    acc[mt][0] =
        __builtin_amdgcn_mfma_f32_16x16x32_bf16(a, tsf[0], acc[mt][0], 0, 0, 0);
    acc[mt][1] =
        __builtin_amdgcn_mfma_f32_16x16x32_bf16(a, tsf[1], acc[mt][1], 0, 0, 0);
  }

#pragma unroll
  for (int mt = 0; mt < 4; ++mt) {
    f32x4 pv = *(const f32x4*)(s_pb + mt * 16 + quad * 4);
#pragma unroll
    for (int nt = 0; nt < 2; ++nt) {
      const int wcol = n0w + nt * 16 + l15;
#pragma unroll
      for (int r = 0; r < 4; ++r) {
        const int o = mt * 16 + quad * 4 + r;
        float v = acc[mt][nt][r];
        float g = fmaf(0.5f * v, 1.f + erff(v * 0.70710678f), pv[r]);
        out[((size_t)(b * 64 + o) * 128 + h) * 128 + wcol] = g;
      }
    }
  }
#undef AR
}

// ---------------------------------------------------------------------------
extern "C" void kernel_launch(void* const* d_in, const int* in_sizes, int n_in,
                              void* d_out, int out_size, void* d_ws,
                              size_t ws_size, hipStream_t stream) {
  (void)in_sizes;
  (void)n_in;
  (void)out_size;
  (void)ws_size;
  const float* x = (const float*)d_in[0];
  const float* t_emb = (const float*)d_in[1];
  const float* wr = (const float*)d_in[2];
  const float* wi = (const float*)d_in[3];
  const float* bw = (const float*)d_in[4];
  const float* bb = (const float*)d_in[5];
  const float* tw = (const float*)d_in[6];
  const float* tb = (const float*)d_in[7];
  float* out = (float*)d_out;

  char* ws = (char*)d_ws;
  float* proj = (float*)(ws);
  float* ofr = (float*)(ws + ((size_t)1 << 20));
  float* ofi = (float*)(ws + ((size_t)2 << 20));
  float* xfr_t = (float*)(ws + ((size_t)3 << 20));
  float* xfi_t = (float*)(ws + ((size_t)4 << 20));
  float* wt_r = (float*)(ws + ((size_t)5 << 20));
  float* wt_i = (float*)(ws + ((size_t)9 << 20));
  float2* Tck = (float2*)(ws + ((size_t)13 << 20));
  unsigned short* Tspec = (unsigned short*)(ws + ((size_t)13 << 20) + 65536);

  front_kernel<<<3089, 256, 0, stream>>>(x, xfr_t, xfi_t, wr, wi, wt_r, wt_i,
                                         t_emb, tw, tb, proj, Tck, Tspec);
  modemix_kernel<<<256, 1024, 0, stream>>>(xfr_t, xfi_t, wt_r, wt_i, ofr, ofi);
  final_kernel<<<dim3(128, 16), 256, 0, stream>>>(x, bw, bb, proj, ofr, ofi,
                                                  Tck, Tspec, out);
}